// Round 11
// baseline (187.902 us; speedup 1.0000x reference)
//
#include <hip/hip_runtime.h>

// MultiHeadSelfAttention: B=2, S=2048, D=1024, H=16, Dh=64, fp32 in/out.
// R25: R24 with (a) cast grid reverted to 256 (1024 was neutral-to-worse),
// (b) gemm_out epilogue vectorized: acc -> LDS [128][68] f32 transpose
// (2-way bank alias on write = free; conflict-free read) -> 8x float4
// per thread in coalesced 256B row-runs (was 32 scalar fp32 stores with
// 4x64B scattered segments per wave). Output bitwise identical.
// attn (R20 exact, empirical floor) / qkv (dual Q+K, dual-V) unchanged.

#define T_TOK 4096
#define DM    1024
#define SQ    2048
#define NH    16
#define DH    64

typedef unsigned short u16;
typedef unsigned int   u32;
typedef __bf16 bf16x8 __attribute__((ext_vector_type(8)));
typedef float  f32x4  __attribute__((ext_vector_type(4)));
typedef float  f32x16 __attribute__((ext_vector_type(16)));
typedef u32    u32x4  __attribute__((ext_vector_type(4)));

__device__ __forceinline__ u16 f2bf(float f) {   // RNE fp32->bf16
  u32 u = __builtin_bit_cast(u32, f);
  u32 r = (u + 0x7FFFu + ((u >> 16) & 1u)) >> 16;
  return (u16)r;
}

#if __has_builtin(__builtin_amdgcn_cvt_pk_bf16_f32)
typedef __bf16 bf16x2 __attribute__((ext_vector_type(2)));
__device__ __forceinline__ u32 pk2bf(float a, float b) {
  bf16x2 h = __builtin_amdgcn_cvt_pk_bf16_f32(a, b);
  return __builtin_bit_cast(u32, h);
}
#else
__device__ __forceinline__ u32 pk2bf(float a, float b) {  // 1 instr on gfx950
  u32 r;
  asm("v_cvt_pk_bf16_f32 %0, %1, %2" : "=v"(r) : "v"(a), "v"(b));
  return r;
}
#endif

__device__ __forceinline__ void gld16(const void* g, void* l) {
  __builtin_amdgcn_global_load_lds(
      (const __attribute__((address_space(1))) u32*)g,
      (__attribute__((address_space(3))) u32*)l, 16, 0, 0);
}

// ---------------- k1: cast to bf16 ----------------
__global__ void cast_bf16_kernel(const float* __restrict__ x,
    const float* __restrict__ w0, const float* __restrict__ w1,
    const float* __restrict__ w2, const float* __restrict__ w3,
    u16* __restrict__ xb, u16* __restrict__ o0, u16* __restrict__ o1,
    u16* __restrict__ o2, u16* __restrict__ o3)
{
  const float* src; u16* dst; int n;
  switch (blockIdx.y) {
    case 0:  src = x;  dst = xb; n = T_TOK * DM; break;
    case 1:  src = w0; dst = o0; n = DM * DM; break;
    case 2:  src = w1; dst = o1; n = DM * DM; break;
    case 3:  src = w2; dst = o2; n = DM * DM; break;
    default: src = w3; dst = o3; n = DM * DM; break;
  }
  const int stride = gridDim.x * blockDim.x;
  for (int i = blockIdx.x * blockDim.x + threadIdx.x; i * 4 < n; i += stride) {
    float4 v = ((const float4*)src)[i];
    ushort4 o;
    o.x = f2bf(v.x); o.y = f2bf(v.y); o.z = f2bf(v.z); o.w = f2bf(v.w);
    ((ushort4*)dst)[i] = o;
  }
}

// ---- dual-A 128x128 NT-GEMM core: C1 = A1 x B, C2 = A2 x B, shared B -------
// Stages 3 panels per K-step for two 128x128 outputs; 64 MFMA/wave/K-step.
__device__ __forceinline__ void gemm_core_qk(
    u16* lds, const u16* __restrict__ Aq, const u16* __restrict__ Ak,
    const u16* __restrict__ Bb, f32x4 accQ[4][4], f32x4 accK[4][4])
{
  u16* As = lds;            // A1 tile [128][64]
  u16* A2 = lds + 8192;     // A2 tile [128][64]
  u16* Bs = lds + 16384;    // B  tile [128][64]
  const int tid = threadIdx.x, lane = tid & 63, w = tid >> 6;
  const int waveM = w >> 1, waveN = w & 1;
  const int col = lane & 15, quad = lane >> 4;
  const int srow = lane >> 3;
  const int sg0  = (lane & 7) ^ srow;

  for (int k0 = 0; k0 < DM; k0 += 64) {
    #pragma unroll
    for (int i = 0; i < 4; ++i) {
      const int rb = w * 32 + i * 8;
      const int sg = sg0 ^ ((rb >> 3) & 3);
      const size_t off = (size_t)(rb + srow) * DM + k0 + sg * 8;
      gld16(Aq + off, &As[rb * 64]);
      gld16(Ak + off, &A2[rb * 64]);
      gld16(Bb + off, &Bs[rb * 64]);
    }
    __syncthreads();
    #pragma unroll
    for (int c = 0; c < 2; ++c) {
      bf16x8 af[4], ag[4], bg[4];
      #pragma unroll
      for (int i = 0; i < 4; ++i) {
        const int row = waveM * 64 + i * 16 + col;
        const int gp = (c * 4 + quad) ^ (row & 7) ^ ((row >> 3) & 3);
        af[i] = *(const bf16x8*)&As[row * 64 + gp * 8];
        ag[i] = *(const bf16x8*)&A2[row * 64 + gp * 8];
      }
      #pragma unroll
      for (int j = 0; j < 4; ++j) {
        const int row = waveN * 64 + j * 16 + col;
        const int gp = (c * 4 + quad) ^ (row & 7) ^ ((row >> 3) & 3);
        bg[j] = *(const bf16x8*)&Bs[row * 64 + gp * 8];
      }
      #pragma unroll
      for (int i = 0; i < 4; ++i) {
        #pragma unroll
        for (int j = 0; j < 4; ++j) {
          accQ[i][j] = __builtin_amdgcn_mfma_f32_16x16x32_bf16(af[i], bg[j], accQ[i][j], 0, 0, 0);
          accK[i][j] = __builtin_amdgcn_mfma_f32_16x16x32_bf16(ag[i], bg[j], accK[i][j], 0, 0, 0);
        }
      }
    }
    __syncthreads();
  }
}

// ---------------- k2: fused QKV projection ----------------
// grid (48, 8), 256 threads:
//   x<32: DUAL Q+K — Wq,Wk share staged x-tile (tb=x); writes Q(scaled), K.
//   x>=32: DUAL V — two x token-tiles (tb0=2tp, tb1=2tp+1) share staged Wv
//          panel; transpose epilogue x2 -> Vt.
__global__ __launch_bounds__(256, 2) void gemm_qkv_kernel(
    const u16* __restrict__ xb,
    const u16* __restrict__ Wqb, const u16* __restrict__ Wkb, const u16* __restrict__ Wvb,
    const float* __restrict__ bq, const float* __restrict__ bk, const float* __restrict__ bv,
    u16* __restrict__ Qs, u16* __restrict__ Kh, u16* __restrict__ Vt)
{
  __shared__ __align__(16) u16 smem[3 * 8192];   // 48 KB
  const int cb = blockIdx.y;                     // channel-block (8)
  const int tid = threadIdx.x;
  const int lane = tid & 63, w = tid >> 6;
  const int waveM = w >> 1, waveN = w & 1;
  const int col = lane & 15, quad = lane >> 4;
  const f32x4 zf = {0.f, 0.f, 0.f, 0.f};

  f32x4 accA[4][4], accB[4][4];
  #pragma unroll
  for (int i = 0; i < 4; ++i)
    #pragma unroll
    for (int j = 0; j < 4; ++j) { accA[i][j] = zf; accB[i][j] = zf; }

  if (blockIdx.x < 32) {                         // ---- dual Q+K path ----
    const int tb = blockIdx.x;
    gemm_core_qk(smem, Wqb + (size_t)(cb * 128) * DM,
                 Wkb + (size_t)(cb * 128) * DM,
                 xb + (size_t)(tb * 128) * DM, accA, accB);
    const float qscale = 0.18033688011112042f;   // log2(e)/8 for Q
    const int chBase  = cb * 128 + waveM * 64;   // A side = channels
    const int tokBase = tb * 128 + waveN * 64;   // B side = tokens
    #pragma unroll
    for (int i = 0; i < 4; ++i) {
      const int c0 = chBase + i * 16 + quad * 4;         // 4 consecutive d
      const int hh = c0 >> 6, d0 = c0 & 63;
      const float4 bbq = *(const float4*)&bq[c0];
      const float4 bbk = *(const float4*)&bk[c0];
      #pragma unroll
      for (int j = 0; j < 4; ++j) {
        const int t = tokBase + j * 16 + col;
        const int b = t >> 11, s = t & 2047;
        const size_t base = ((size_t)(b * NH + hh) * SQ + s) * DH + d0;
        ushort4 pq;
        pq.x = f2bf((accA[i][j][0] + bbq.x) * qscale);
        pq.y = f2bf((accA[i][j][1] + bbq.y) * qscale);
        pq.z = f2bf((accA[i][j][2] + bbq.z) * qscale);
        pq.w = f2bf((accA[i][j][3] + bbq.w) * qscale);
        *(ushort4*)&Qs[base] = pq;
        ushort4 pk;
        pk.x = f2bf(accB[i][j][0] + bbk.x);
        pk.y = f2bf(accB[i][j][1] + bbk.y);
        pk.z = f2bf(accB[i][j][2] + bbk.z);
        pk.w = f2bf(accB[i][j][3] + bbk.w);
        *(ushort4*)&Kh[base] = pk;
      }
    }
  } else {                                       // ---- dual V path ----
    const int tp = blockIdx.x - 32;              // token-pair (16)
    gemm_core_qk(smem, xb + (size_t)(tp * 256) * DM,
                 xb + (size_t)(tp * 256 + 128) * DM,
                 Wvb + (size_t)(cb * 128) * DM, accA, accB);
    // core ends with __syncthreads(); panels dead -> reuse as transpose tile
    u16* tr = smem;
    #pragma unroll
    for (int pass = 0; pass < 2; ++pass) {
      f32x4 (*acc)[4] = pass ? accB : accA;
      #pragma unroll
      for (int j = 0; j < 4; ++j) {
        const int cl = waveN * 64 + j * 16 + col;        // channel (B side)
        const float bb = bv[cb * 128 + cl];
        #pragma unroll
        for (int i = 0; i < 4; ++i) {
          const int tl = waveM * 64 + i * 16 + quad * 4; // token (A side)
          ushort4 pk;
          pk.x = f2bf(acc[i][j][0] + bb); pk.y = f2bf(acc[i][j][1] + bb);
          pk.z = f2bf(acc[i][j][2] + bb); pk.w = f2bf(acc[i][j][3] + bb);
          *(ushort4*)&tr[cl * 136 + tl] = pk;
        }
      }
      __syncthreads();
      const int t0 = tp * 256 + pass * 128;
      const int b = t0 >> 11, sBase = t0 & 2047;
      #pragma unroll
      for (int rep = 0; rep < 8; ++rep) {
        const int chunk = rep * 256 + tid;
        const int row = chunk >> 4, off = (chunk & 15) * 8;
        const int c = cb * 128 + row;
        const int hh = c >> 6, d = c & 63;
        uint4 v = *(const uint4*)&tr[row * 136 + off];
        *(uint4*)&Vt[((size_t)(b * NH + hh) * DH + d) * SQ + sBase + off] = v;
      }
      __syncthreads();   // write done before tr refill (pass 0 only matters)
    }
  }
}

// ---------------- k4: flash attention, q-tile 128, full-s' waves ------------
// [R20 exact — empirical floor of this dataflow: 45.8us]
// grid (B*H, S/128) — bh on x so XCD = bh%8 (K/V L2-resident).
// block 256 = 4 waves; wave w owns q slice q0 + w*32 .. +32 over the FULL
// 64-s' tile: per iter 8 QK MFMA + 8 PV MFMA. cacc final per wave ->
// direct store. K/V double-buffered 8KB tiles (32KB), 2 blocks/CU.
__global__ __launch_bounds__(256, 2) void attn_kernel(
    const u16* __restrict__ Qs, const u16* __restrict__ Kh,
    const u16* __restrict__ Vt, u16* __restrict__ ctx)
{
  __shared__ __align__(16) char smem[32 * 1024];
  u16* KtB = (u16*)smem;                    // 2 x [64][64] swz, 4096 u16 each
  u16* VlB = (u16*)(smem + 16384);          // 2 x [64][64] swz, 4096 u16 each

  const int tid = threadIdx.x, lane = tid & 63, w = tid >> 6;
  const int l31 = lane & 31, h = lane >> 5;
  const int bh = blockIdx.x, q0 = blockIdx.y * 128;
  const u16* Qb = Qs + ((size_t)bh * SQ + q0) * DH;
  const u16* Kb = Kh + (size_t)bh * SQ * DH;
  const u16* Vb = Vt + (size_t)bh * DH * SQ;
  const int srow = lane >> 3;               // staging row-in-group 0..7
  const int sgl  = (lane & 7) ^ srow;       // staging swizzle, rb part below

  // Q B-frags (this wave's 32 q): n = q = q0 + w*32 + l31, k = 16ks+8h+j
  bf16x8 qreg[4];
  #pragma unroll
  for (int ks = 0; ks < 4; ++ks)
    qreg[ks] = *(const bf16x8*)(Qb + (size_t)(w * 32 + l31) * DH + ks * 16 + h * 8);

  // stage tile 0 into buffer 0 (each wave: 16 rows of K, 16 rows of V)
  #pragma unroll
  for (int i = 0; i < 2; ++i) {
    const int rb = w * 16 + i * 8;
    const int sg = sgl ^ ((rb >> 3) & 3);
    gld16(Kb + (size_t)(rb + srow) * DH + sg * 8, &KtB[rb * 64]);
    gld16(Vb + (size_t)(rb + srow) * SQ + sg * 8, &VlB[rb * 64]);
  }

  f32x16 cacc[2];                    // [dt] ctx^T (64d x 32q), FINAL per wave
  #pragma unroll
  for (int dt = 0; dt < 2; ++dt)
    #pragma unroll
    for (int e = 0; e < 16; ++e) cacc[dt][e] = 0.f;
  float l_s = 0.f;
  __syncthreads();

  for (int kt = 0; kt < SQ / 64; ++kt) {
    const int cur = kt & 1;
    u16* Kt = KtB + cur * 4096;
    u16* Vl = VlB + cur * 4096;
    if (kt + 1 < SQ / 64) {                // prefetch next tile into other buf
      const int nxt = cur ^ 1, s1 = (kt + 1) * 64;
      u16* Ktn = KtB + nxt * 4096;
      u16* Vln = VlB + nxt * 4096;
      #pragma unroll
      for (int i = 0; i < 2; ++i) {
        const int rb = w * 16 + i * 8;
        const int sg = sgl ^ ((rb >> 3) & 3);
        gld16(Kb + (size_t)(s1 + rb + srow) * DH + sg * 8, &Ktn[rb * 64]);
        gld16(Vb + (size_t)(rb + srow) * SQ + s1 + sg * 8, &Vln[rb * 64]);
      }
    }

    // S^T = K Q^T over BOTH 32-s' halves (keys for row 32+l31 ≡ row l31)
    f32x16 sacc0 = {}, sacc1 = {};
    __builtin_amdgcn_s_setprio(1);
    #pragma unroll
    for (int ks = 0; ks < 4; ++ks) {
      const int gp = ((2 * ks + h) ^ (l31 & 7) ^ ((l31 >> 3) & 3)) * 8;
      bf16x8 kf0 = *(const bf16x8*)&Kt[l31 * 64 + gp];
      bf16x8 kf1 = *(const bf16x8*)&Kt[(32 + l31) * 64 + gp];
      sacc0 = __builtin_amdgcn_mfma_f32_32x32x16_bf16(kf0, qreg[ks], sacc0, 0, 0, 0);
      sacc1 = __builtin_amdgcn_mfma_f32_32x32x16_bf16(kf1, qreg[ks], sacc1, 0, 0, 0);
    }
    __builtin_amdgcn_s_setprio(0);

    // softmax p = exp2(s), both halves; Pp[hs][rg][u]: s'loc = 32hs+8rg+4h+2u
    u32 Pp[2][4][2];
    {
      float p[16], q[16];
      #pragma unroll
      for (int e = 0; e < 16; ++e) {
        p[e] = __builtin_amdgcn_exp2f(sacc0[e]);
        q[e] = __builtin_amdgcn_exp2f(sacc1[e]);
      }
      float t0 = (p[0] + p[1]) + (p[2] + p[3]);
      float t1 = (p[4] + p[5]) + (p[6] + p[7]);
      float t2 = (p[8] + p[9]) + (p[10] + p[11]);
      float t3 = (p[12] + p[13]) + (p[14] + p[15]);
      float u0 = (q[0] + q[1]) + (q[2] + q[3]);
      float u1 = (q[4] + q[5]) + (q[6] + q[7]);
      float u2 = (q[8] + q[9]) + (q[10] + q[11]);
      float u3 = (q[12] + q[13]) + (q[14] + q[15]);
      l_s += ((t0 + t1) + (t2 + t3)) + ((u0 + u1) + (u2 + u3));
      #pragma unroll
      for (int rg = 0; rg < 4; ++rg) {
        Pp[0][rg][0] = pk2bf(p[4 * rg + 0], p[4 * rg + 1]);
        Pp[0][rg][1] = pk2bf(p[4 * rg + 2], p[4 * rg + 3]);
        Pp[1][rg][0] = pk2bf(q[4 * rg + 0], q[4 * rg + 1]);
        Pp[1][rg][1] = pk2bf(q[4 * rg + 2], q[4 * rg + 3]);
      }
    }

    // ctx^T += V^T P^T: 4 ksteps over 64 s' (ksg), both d-halves
    __builtin_amdgcn_s_setprio(1);
    #pragma unroll
    for (int ksg = 0; ksg < 4; ++ksg) {
      const int hs = ksg >> 1, p2 = ksg & 1;
      u32 a0 = Pp[hs][2 * p2][0], b0 = Pp[hs][2 * p2 + 1][0];
      u32 a1 = Pp[hs][2 * p2][1], b1 = Pp[hs][2 * p2 + 1][1];
      asm("v_permlane32_swap_b32 %0, %1" : "+v"(a0), "+v"(b0));
      asm("v_permlane32_swap_b32 %0, %1" : "+v"(a1), "+v"(b1));
      u32x4 fw;
      fw.x = a0; fw.y = a1; fw.z = b0; fw.w = b1;
      bf16x8 pf = __builtin_bit_cast(bf16x8, fw);
      const int gp = ((2 * ksg + h) ^ (l31 & 7) ^ ((l31 >> 3) & 3)) * 8;
      bf16x8 vf0 = *(const bf16x8*)&Vl[l31 * 64 + gp];
      bf16x8 vf1 = *(const bf16x8*)&Vl[(32 + l31) * 64 + gp];
      cacc[0] = __builtin_amdgcn_mfma_f32_32x32x16_bf16(vf0, pf, cacc[0], 0, 0, 0);
      cacc[1] = __builtin_amdgcn_mfma_f32_32x32x16_bf16(vf1, pf, cacc[1], 0, 0, 0);
    }
    __builtin_amdgcn_s_setprio(0);
    __syncthreads();   // buffer-swap fence + prefetch drain
  }

  // ----- epilogue: cacc is final per wave; direct scaled store -----
  const float lq = l_s + __shfl_xor(l_s, 32, 64);
  const float inv = 1.0f / lq;
  const int b = bh >> 4, hd = bh & 15;
  const int s = q0 + w * 32 + l31;
  #pragma unroll
  for (int dt = 0; dt < 2; ++dt) {
    #pragma unroll
    for (int c = 0; c < 4; ++c) {
      const int d0 = dt * 32 + c * 8 + 4 * h;
      ushort4 pk;
      pk.x = f2bf(cacc[dt][4 * c + 0] * inv);
      pk.y = f2bf(cacc[dt][4 * c + 1] * inv);
      pk.z = f2bf(cacc[dt][4 * c + 2] * inv);
      pk.w = f2bf(cacc[dt][4 * c + 3] * inv);
      *(ushort4*)&ctx[(size_t)(b * SQ + s) * DM + hd * DH + d0] = pk;
    }
  }
}

// ------------- 128x64 NT-GEMM core (A=128 rows, B=64 rows, BK=64) ------------
__device__ __forceinline__ void gemm_core_128x64(
    u16* lds, const u16* __restrict__ Ab, const u16* __restrict__ Bb,
    f32x4 acc[4][2])
{
  u16* As = lds;            // [128][64]
  u16* Bs = lds + 8192;     // [64][64]
  const int tid = threadIdx.x, lane = tid & 63, w = tid >> 6;
  const int waveM = w >> 1, waveN = w & 1;
  const int col = lane & 15, quad = lane >> 4;
  const int srow = lane >> 3;
  const int sg0  = (lane & 7) ^ srow;

  for (int k0 = 0; k0 < DM; k0 += 64) {
    #pragma unroll
    for (int i = 0; i < 4; ++i) {
      const int rb = w * 32 + i * 8;
      const int sg = sg0 ^ ((rb >> 3) & 3);
      gld16(Ab + (size_t)(rb + srow) * DM + k0 + sg * 8, &As[rb * 64]);
    }
    #pragma unroll
    for (int i = 0; i < 2; ++i) {
      const int rb = w * 16 + i * 8;
      const int sg = sg0 ^ ((rb >> 3) & 3);
      gld16(Bb + (size_t)(rb + srow) * DM + k0 + sg * 8, &Bs[rb * 64]);
    }
    __syncthreads();
    #pragma unroll
    for (int c = 0; c < 2; ++c) {
      bf16x8 af[4], bg[2];
      #pragma unroll
      for (int i = 0; i < 4; ++i) {
        const int row = waveM * 64 + i * 16 + col;
        const int gp = (c * 4 + quad) ^ (row & 7) ^ ((row >> 3) & 3);
        af[i] = *(const bf16x8*)&As[row * 64 + gp * 8];
      }
      #pragma unroll
      for (int j = 0; j < 2; ++j) {
        const int row = waveN * 32 + j * 16 + col;
        const int gp = (c * 4 + quad) ^ (row & 7) ^ ((row >> 3) & 3);
        bg[j] = *(const bf16x8*)&Bs[row * 64 + gp * 8];
      }
      #pragma unroll
      for (int i = 0; i < 4; ++i) {
        #pragma unroll
        for (int j = 0; j < 2; ++j)
          acc[i][j] = __builtin_amdgcn_mfma_f32_16x16x32_bf16(af[i], bg[j], acc[i][j], 0, 0, 0);
      }
    }
    __syncthreads();
  }
}

// -------- k5: output projection (128x64 tiles, BK=64 swizzled, fp32 out) -----
// grid (32, 16) — token-block on x so XCD = token-group.
// R25: epilogue via LDS [128][68] f32 transpose -> coalesced float4 stores
// (256B row-runs), replacing 32 scalar stores/thread. Bitwise-identical out.
__global__ __launch_bounds__(256) void gemm_out_kernel(
    const u16* __restrict__ ctx, const u16* __restrict__ Wob,
    const float* __restrict__ bo, float* __restrict__ out)
{
  __shared__ __align__(16) char smem[128 * 68 * 4];   // 34 KB (core uses 24)
  const int tb = blockIdx.x;                 // token-block (32)
  const int cb = blockIdx.y;                 // channel-block (16)
  const int tid = threadIdx.x, lane = tid & 63, w = tid >> 6;
  const int waveM = w >> 1, waveN = w & 1;
  const int col = lane & 15, quad = lane >> 4;

  f32x4 acc[4][2];
  const f32x4 zf = {0.f, 0.f, 0.f, 0.f};
  #pragma unroll
  for (int i = 0; i < 4; ++i) {
    #pragma unroll
    for (int j = 0; j < 2; ++j) acc[i][j] = zf;
  }

  gemm_core_128x64((u16*)smem, ctx + (size_t)(tb * 128) * DM,
                   Wob + (size_t)(cb * 64) * DM, acc);

  // core ends with __syncthreads(); As/Bs dead -> f32 transpose tile
  float* tr = (float*)smem;                  // [128][68]
  #pragma unroll
  for (int j = 0; j < 2; ++j) {
    const int cl = waveN * 32 + j * 16 + col;        // local channel 0..63
    const float bb = bo[cb * 64 + cl];
    #pragma unroll
    for (int i = 0; i < 4; ++i) {
      #pragma unroll
      for (int r = 0; r < 4; ++r) {
        const int tl = waveM * 64 + i * 16 + quad * 4 + r;   // local token
        tr[tl * 68 + cl] = acc[i][j][r] + bb;
      }
    }
  }
  __syncthreads();
  const int t0 = tb * 128, c0 = cb * 64;
  #pragma unroll
  for (int rep = 0; rep < 8; ++rep) {
    const int chunk = rep * 256 + tid;       // 2048 float4 chunks
    const int row = chunk >> 4;              // 0..127
    const int off = (chunk & 15) * 4;        // 0..60
    float4 v = *(const float4*)&tr[row * 68 + off];
    *(float4*)&out[(size_t)(t0 + row) * DM + c0 + off] = v;
  }
}

extern "C" void kernel_launch(void* const* d_in, const int* in_sizes, int n_in,
                              void* d_out, int out_size, void* d_ws, size_t ws_size,
                              hipStream_t stream) {
  const float* x  = (const float*)d_in[0];
  const float* Wq = (const float*)d_in[1];
  const float* bq = (const float*)d_in[2];
  const float* Wk = (const float*)d_in[3];
  const float* bk = (const float*)d_in[4];
  const float* Wv = (const float*)d_in[5];
  const float* bv = (const float*)d_in[6];
  const float* Wo = (const float*)d_in[7];
  const float* bo = (const float*)d_in[8];

  char* ws = (char*)d_ws;                  // 40 MB used
  u16* xb  = (u16*)(ws);                   // 8 MB  (reused as ctx after QKV)
  u16* Wqb = (u16*)(ws + (8ull  << 20));   // 2 MB
  u16* Wkb = (u16*)(ws + (10ull << 20));   // 2 MB
  u16* Wvb = (u16*)(ws + (12ull << 20));   // 2 MB
  u16* Wob = (u16*)(ws + (14ull << 20));   // 2 MB
  u16* Qs  = (u16*)(ws + (16ull << 20));   // 8 MB  [b,h,s,d], pre-scaled
  u16* Kh  = (u16*)(ws + (24ull << 20));   // 8 MB  [b,h,s,d]
  u16* Vt  = (u16*)(ws + (32ull << 20));   // 8 MB  [b,h,d,s]
  u16* ctx = xb;                           // alias: xb dead after QKV GEMM

  cast_bf16_kernel<<<dim3(256, 5), 256, 0, stream>>>(x, Wq, Wk, Wv, Wo,
                                                     xb, Wqb, Wkb, Wvb, Wob);
  gemm_qkv_kernel<<<dim3(48, 8), 256, 0, stream>>>(xb, Wqb, Wkb, Wvb,
                                                   bq, bk, bv, Qs, Kh, Vt);
  attn_kernel<<<dim3(32, 16), 256, 0, stream>>>(Qs, Kh, Vt, ctx);
  gemm_out_kernel<<<dim3(32, 16), 256, 0, stream>>>(ctx, Wob, bo, (float*)d_out);
  (void)in_sizes; (void)n_in; (void)out_size; (void)ws_size;
}

// Round 12
// 181.312 us; speedup vs baseline: 1.0363x; 1.0363x over previous
//
#include <hip/hip_runtime.h>

// MultiHeadSelfAttention: B=2, S=2048, D=1024, H=16, Dh=64, fp32 in/out.
// R26 = R20 byte-exact (best-measured: 180.1us). Session summary:
//  - attn: q-tile 128, 4 waves, full-s' per wave, direct store, permlane32
//    P-exchange, XCD-local bh-on-x (45.8us; R17/R18/R22/R23 rewrites all
//    failed to beat it -> empirical floor of this dataflow).
//  - qkv: dual Q+K GEMM sharing the staged x-tile (R19, -11us) + single V.
//  - out: 128x64 core, scalar epilogue (R25's LDS-transpose store cut
//    occupancy 6->4 blocks/CU and regressed; reverted).
//  - cast: grid 256 (1024 was neutral).
// Post-R20 composites (R22-R25) all drifted +2..+8us -> locked to R20.

#define T_TOK 4096
#define DM    1024
#define SQ    2048
#define NH    16
#define DH    64

typedef unsigned short u16;
typedef unsigned int   u32;
typedef __bf16 bf16x8 __attribute__((ext_vector_type(8)));
typedef float  f32x4  __attribute__((ext_vector_type(4)));
typedef float  f32x16 __attribute__((ext_vector_type(16)));
typedef u32    u32x4  __attribute__((ext_vector_type(4)));

__device__ __forceinline__ u16 f2bf(float f) {   // RNE fp32->bf16
  u32 u = __builtin_bit_cast(u32, f);
  u32 r = (u + 0x7FFFu + ((u >> 16) & 1u)) >> 16;
  return (u16)r;
}

#if __has_builtin(__builtin_amdgcn_cvt_pk_bf16_f32)
typedef __bf16 bf16x2 __attribute__((ext_vector_type(2)));
__device__ __forceinline__ u32 pk2bf(float a, float b) {
  bf16x2 h = __builtin_amdgcn_cvt_pk_bf16_f32(a, b);
  return __builtin_bit_cast(u32, h);
}
#else
__device__ __forceinline__ u32 pk2bf(float a, float b) {  // 1 instr on gfx950
  u32 r;
  asm("v_cvt_pk_bf16_f32 %0, %1, %2" : "=v"(r) : "v"(a), "v"(b));
  return r;
}
#endif

__device__ __forceinline__ void gld16(const void* g, void* l) {
  __builtin_amdgcn_global_load_lds(
      (const __attribute__((address_space(1))) u32*)g,
      (__attribute__((address_space(3))) u32*)l, 16, 0, 0);
}

// ---------------- k1: cast to bf16 ----------------
__global__ void cast_bf16_kernel(const float* __restrict__ x,
    const float* __restrict__ w0, const float* __restrict__ w1,
    const float* __restrict__ w2, const float* __restrict__ w3,
    u16* __restrict__ xb, u16* __restrict__ o0, u16* __restrict__ o1,
    u16* __restrict__ o2, u16* __restrict__ o3)
{
  const float* src; u16* dst; int n;
  switch (blockIdx.y) {
    case 0:  src = x;  dst = xb; n = T_TOK * DM; break;
    case 1:  src = w0; dst = o0; n = DM * DM; break;
    case 2:  src = w1; dst = o1; n = DM * DM; break;
    case 3:  src = w2; dst = o2; n = DM * DM; break;
    default: src = w3; dst = o3; n = DM * DM; break;
  }
  const int stride = gridDim.x * blockDim.x;
  for (int i = blockIdx.x * blockDim.x + threadIdx.x; i * 4 < n; i += stride) {
    float4 v = ((const float4*)src)[i];
    ushort4 o;
    o.x = f2bf(v.x); o.y = f2bf(v.y); o.z = f2bf(v.z); o.w = f2bf(v.w);
    ((ushort4*)dst)[i] = o;
  }
}

// ------------- shared 128x128 NT-GEMM core (K=1024, BK=64, swizzled) ---------
__device__ __forceinline__ void gemm_core_128x128(
    u16* lds, const u16* __restrict__ Ab, const u16* __restrict__ Bb,
    f32x4 acc[4][4])
{
  u16* As = lds;
  u16* Bs = lds + 8192;
  const int tid = threadIdx.x, lane = tid & 63, w = tid >> 6;
  const int waveM = w >> 1, waveN = w & 1;
  const int col = lane & 15, quad = lane >> 4;
  const int srow = lane >> 3;                  // 0..7
  const int sg0  = (lane & 7) ^ srow;          // swizzle, rb-part added below

  for (int k0 = 0; k0 < DM; k0 += 64) {
    #pragma unroll
    for (int i = 0; i < 4; ++i) {
      const int rb = w * 32 + i * 8;
      const int sg = sg0 ^ ((rb >> 3) & 3);
      gld16(Ab + (size_t)(rb + srow) * DM + k0 + sg * 8, &As[rb * 64]);
      gld16(Bb + (size_t)(rb + srow) * DM + k0 + sg * 8, &Bs[rb * 64]);
    }
    __syncthreads();
    #pragma unroll
    for (int c = 0; c < 2; ++c) {
      bf16x8 af[4], bg[4];
      #pragma unroll
      for (int i = 0; i < 4; ++i) {
        const int row = waveM * 64 + i * 16 + col;
        const int gp = (c * 4 + quad) ^ (row & 7) ^ ((row >> 3) & 3);
        af[i] = *(const bf16x8*)&As[row * 64 + gp * 8];
      }
      #pragma unroll
      for (int j = 0; j < 4; ++j) {
        const int row = waveN * 64 + j * 16 + col;
        const int gp = (c * 4 + quad) ^ (row & 7) ^ ((row >> 3) & 3);
        bg[j] = *(const bf16x8*)&Bs[row * 64 + gp * 8];
      }
      #pragma unroll
      for (int i = 0; i < 4; ++i) {
        #pragma unroll
        for (int j = 0; j < 4; ++j)
          acc[i][j] = __builtin_amdgcn_mfma_f32_16x16x32_bf16(af[i], bg[j], acc[i][j], 0, 0, 0);
      }
    }
    __syncthreads();
  }
}

// ---- dual-A 128x128 NT-GEMM core: C1 = Aq x B, C2 = Ak x B, shared B -------
__device__ __forceinline__ void gemm_core_qk(
    u16* lds, const u16* __restrict__ Aq, const u16* __restrict__ Ak,
    const u16* __restrict__ Bb, f32x4 accQ[4][4], f32x4 accK[4][4])
{
  u16* As = lds;            // Wq tile [128][64]
  u16* A2 = lds + 8192;     // Wk tile [128][64]
  u16* Bs = lds + 16384;    // x  tile [128][64]
  const int tid = threadIdx.x, lane = tid & 63, w = tid >> 6;
  const int waveM = w >> 1, waveN = w & 1;
  const int col = lane & 15, quad = lane >> 4;
  const int srow = lane >> 3;
  const int sg0  = (lane & 7) ^ srow;

  for (int k0 = 0; k0 < DM; k0 += 64) {
    #pragma unroll
    for (int i = 0; i < 4; ++i) {
      const int rb = w * 32 + i * 8;
      const int sg = sg0 ^ ((rb >> 3) & 3);
      const size_t off = (size_t)(rb + srow) * DM + k0 + sg * 8;
      gld16(Aq + off, &As[rb * 64]);
      gld16(Ak + off, &A2[rb * 64]);
      gld16(Bb + off, &Bs[rb * 64]);
    }
    __syncthreads();
    #pragma unroll
    for (int c = 0; c < 2; ++c) {
      bf16x8 af[4], ag[4], bg[4];
      #pragma unroll
      for (int i = 0; i < 4; ++i) {
        const int row = waveM * 64 + i * 16 + col;
        const int gp = (c * 4 + quad) ^ (row & 7) ^ ((row >> 3) & 3);
        af[i] = *(const bf16x8*)&As[row * 64 + gp * 8];
        ag[i] = *(const bf16x8*)&A2[row * 64 + gp * 8];
      }
      #pragma unroll
      for (int j = 0; j < 4; ++j) {
        const int row = waveN * 64 + j * 16 + col;
        const int gp = (c * 4 + quad) ^ (row & 7) ^ ((row >> 3) & 3);
        bg[j] = *(const bf16x8*)&Bs[row * 64 + gp * 8];
      }
      #pragma unroll
      for (int i = 0; i < 4; ++i) {
        #pragma unroll
        for (int j = 0; j < 4; ++j) {
          accQ[i][j] = __builtin_amdgcn_mfma_f32_16x16x32_bf16(af[i], bg[j], accQ[i][j], 0, 0, 0);
          accK[i][j] = __builtin_amdgcn_mfma_f32_16x16x32_bf16(ag[i], bg[j], accK[i][j], 0, 0, 0);
        }
      }
    }
    __syncthreads();
  }
}

// ---------------- k2: fused QKV projection ----------------
// grid (32, 8, 2) — token-block on x so XCD = token-group:
//   z=0: DUAL GEMM — Wq+Wk share the staged x-tile; writes Q (scaled), K.
//   z=1: A = x rows (tb), B = Wv rows (cb) + transpose -> Vt.
__global__ __launch_bounds__(256, 2) void gemm_qkv_kernel(
    const u16* __restrict__ xb,
    const u16* __restrict__ Wqb, const u16* __restrict__ Wkb, const u16* __restrict__ Wvb,
    const float* __restrict__ bq, const float* __restrict__ bk, const float* __restrict__ bv,
    u16* __restrict__ Qs, u16* __restrict__ Kh, u16* __restrict__ Vt)
{
  __shared__ __align__(16) u16 smem[3 * 8192];   // 48 KB (z=1 uses 34 KB)
  const int z = blockIdx.z;
  const int tb = blockIdx.x;                     // token-block (32)
  const int cb = blockIdx.y;                     // channel-block (8)

  const int tid = threadIdx.x;
  const int lane = tid & 63, w = tid >> 6;
  const int waveM = w >> 1, waveN = w & 1;
  const int col = lane & 15, quad = lane >> 4;
  const f32x4 zf = {0.f, 0.f, 0.f, 0.f};

  if (z == 1) {                                  // ---- V path ----
    u16* tr = smem;
    f32x4 acc[4][4];
    #pragma unroll
    for (int i = 0; i < 4; ++i)
      #pragma unroll
      for (int j = 0; j < 4; ++j) acc[i][j] = zf;
    gemm_core_128x128(smem, xb + (size_t)(tb * 128) * DM,
                      Wvb + (size_t)(cb * 128) * DM, acc);
    #pragma unroll
    for (int j = 0; j < 4; ++j) {
      const int cl = waveN * 64 + j * 16 + col;
      const float bb = bv[cb * 128 + cl];
      #pragma unroll
      for (int i = 0; i < 4; ++i) {
        const int tl = waveM * 64 + i * 16 + quad * 4;
        ushort4 pk;
        pk.x = f2bf(acc[i][j][0] + bb); pk.y = f2bf(acc[i][j][1] + bb);
        pk.z = f2bf(acc[i][j][2] + bb); pk.w = f2bf(acc[i][j][3] + bb);
        *(ushort4*)&tr[cl * 136 + tl] = pk;
      }
    }
    __syncthreads();
    const int t0 = tb * 128;
    const int b = t0 >> 11, sBase = t0 & 2047;
    #pragma unroll
    for (int rep = 0; rep < 8; ++rep) {
      const int chunk = rep * 256 + tid;
      const int row = chunk >> 4, off = (chunk & 15) * 8;
      const int c = cb * 128 + row;
      const int h = c >> 6, d = c & 63;
      uint4 v = *(const uint4*)&tr[row * 136 + off];
      *(uint4*)&Vt[((size_t)(b * NH + h) * DH + d) * SQ + sBase + off] = v;
    }
  } else {                                       // ---- fused Q+K path ----
    f32x4 accQ[4][4], accK[4][4];
    #pragma unroll
    for (int i = 0; i < 4; ++i)
      #pragma unroll
      for (int j = 0; j < 4; ++j) { accQ[i][j] = zf; accK[i][j] = zf; }
    gemm_core_qk(smem, Wqb + (size_t)(cb * 128) * DM,
                 Wkb + (size_t)(cb * 128) * DM,
                 xb + (size_t)(tb * 128) * DM, accQ, accK);
    const float qscale = 0.18033688011112042f;   // log2(e)/8 for Q
    const int chBase  = cb * 128 + waveM * 64;   // A side = channels
    const int tokBase = tb * 128 + waveN * 64;   // B side = tokens
    #pragma unroll
    for (int i = 0; i < 4; ++i) {
      const int c0 = chBase + i * 16 + quad * 4;         // 4 consecutive d
      const int hh = c0 >> 6, d0 = c0 & 63;
      const float4 bbq = *(const float4*)&bq[c0];
      const float4 bbk = *(const float4*)&bk[c0];
      #pragma unroll
      for (int j = 0; j < 4; ++j) {
        const int t = tokBase + j * 16 + col;
        const int b = t >> 11, s = t & 2047;
        const size_t base = ((size_t)(b * NH + hh) * SQ + s) * DH + d0;
        ushort4 pq;
        pq.x = f2bf((accQ[i][j][0] + bbq.x) * qscale);
        pq.y = f2bf((accQ[i][j][1] + bbq.y) * qscale);
        pq.z = f2bf((accQ[i][j][2] + bbq.z) * qscale);
        pq.w = f2bf((accQ[i][j][3] + bbq.w) * qscale);
        *(ushort4*)&Qs[base] = pq;
        ushort4 pk;
        pk.x = f2bf(accK[i][j][0] + bbk.x);
        pk.y = f2bf(accK[i][j][1] + bbk.y);
        pk.z = f2bf(accK[i][j][2] + bbk.z);
        pk.w = f2bf(accK[i][j][3] + bbk.w);
        *(ushort4*)&Kh[base] = pk;
      }
    }
  }
}

// ---------------- k4: flash attention, q-tile 128, full-s' waves ------------
// grid (B*H, S/128) — bh on x so XCD = bh%8 (K/V L2-resident).
// block 256 = 4 waves; wave w owns q slice q0 + w*32 .. +32 over the FULL
// 64-s' tile: per iter 8 QK MFMA (2 s'-halves) + 8 PV MFMA. cacc is final
// per wave -> direct store, no cross-wave reduction. P-exchange via
// v_permlane32_swap. K/V staged double-buffered 8KB tiles (32KB total),
// 2 blocks/CU. [empirical floor: 45.8us]
__global__ __launch_bounds__(256, 2) void attn_kernel(
    const u16* __restrict__ Qs, const u16* __restrict__ Kh,
    const u16* __restrict__ Vt, u16* __restrict__ ctx)
{
  __shared__ __align__(16) char smem[32 * 1024];
  u16* KtB = (u16*)smem;                    // 2 x [64][64] swz, 4096 u16 each
  u16* VlB = (u16*)(smem + 16384);          // 2 x [64][64] swz, 4096 u16 each

  const int tid = threadIdx.x, lane = tid & 63, w = tid >> 6;
  const int l31 = lane & 31, h = lane >> 5;
  const int bh = blockIdx.x, q0 = blockIdx.y * 128;
  const u16* Qb = Qs + ((size_t)bh * SQ + q0) * DH;
  const u16* Kb = Kh + (size_t)bh * SQ * DH;
  const u16* Vb = Vt + (size_t)bh * DH * SQ;
  const int srow = lane >> 3;               // staging row-in-group 0..7
  const int sgl  = (lane & 7) ^ srow;       // staging swizzle, rb part below

  // Q B-frags (this wave's 32 q): n = q = q0 + w*32 + l31, k = 16ks+8h+j
  bf16x8 qreg[4];
  #pragma unroll
  for (int ks = 0; ks < 4; ++ks)
    qreg[ks] = *(const bf16x8*)(Qb + (size_t)(w * 32 + l31) * DH + ks * 16 + h * 8);

  // stage tile 0 into buffer 0 (each wave: 16 rows of K, 16 rows of V)
  #pragma unroll
  for (int i = 0; i < 2; ++i) {
    const int rb = w * 16 + i * 8;
    const int sg = sgl ^ ((rb >> 3) & 3);
    gld16(Kb + (size_t)(rb + srow) * DH + sg * 8, &KtB[rb * 64]);
    gld16(Vb + (size_t)(rb + srow) * SQ + sg * 8, &VlB[rb * 64]);
  }

  f32x16 cacc[2];                    // [dt] ctx^T (64d x 32q), FINAL per wave
  #pragma unroll
  for (int dt = 0; dt < 2; ++dt)
    #pragma unroll
    for (int e = 0; e < 16; ++e) cacc[dt][e] = 0.f;
  float l_s = 0.f;
  __syncthreads();

  for (int kt = 0; kt < SQ / 64; ++kt) {
    const int cur = kt & 1;
    u16* Kt = KtB + cur * 4096;
    u16* Vl = VlB + cur * 4096;
    if (kt + 1 < SQ / 64) {                // prefetch next tile into other buf
      const int nxt = cur ^ 1, s1 = (kt + 1) * 64;
      u16* Ktn = KtB + nxt * 4096;
      u16* Vln = VlB + nxt * 4096;
      #pragma unroll
      for (int i = 0; i < 2; ++i) {
        const int rb = w * 16 + i * 8;
        const int sg = sgl ^ ((rb >> 3) & 3);
        gld16(Kb + (size_t)(s1 + rb + srow) * DH + sg * 8, &Ktn[rb * 64]);
        gld16(Vb + (size_t)(rb + srow) * SQ + s1 + sg * 8, &Vln[rb * 64]);
      }
    }

    // S^T = K Q^T over BOTH 32-s' halves (keys for row 32+l31 ≡ row l31)
    f32x16 sacc0 = {}, sacc1 = {};
    __builtin_amdgcn_s_setprio(1);
    #pragma unroll
    for (int ks = 0; ks < 4; ++ks) {
      const int gp = ((2 * ks + h) ^ (l31 & 7) ^ ((l31 >> 3) & 3)) * 8;
      bf16x8 kf0 = *(const bf16x8*)&Kt[l31 * 64 + gp];
      bf16x8 kf1 = *(const bf16x8*)&Kt[(32 + l31) * 64 + gp];
      sacc0 = __builtin_amdgcn_mfma_f32_32x32x16_bf16(kf0, qreg[ks], sacc0, 0, 0, 0);
      sacc1 = __builtin_amdgcn_mfma_f32_32x32x16_bf16(kf1, qreg[ks], sacc1, 0, 0, 0);
    }
    __builtin_amdgcn_s_setprio(0);

    // softmax p = exp2(s), both halves; Pp[hs][rg][u]: s'loc = 32hs+8rg+4h+2u
    u32 Pp[2][4][2];
    {
      float p[16], q[16];
      #pragma unroll
      for (int e = 0; e < 16; ++e) {
        p[e] = __builtin_amdgcn_exp2f(sacc0[e]);
        q[e] = __builtin_amdgcn_exp2f(sacc1[e]);
      }
      float t0 = (p[0] + p[1]) + (p[2] + p[3]);
      float t1 = (p[4] + p[5]) + (p[6] + p[7]);
      float t2 = (p[8] + p[9]) + (p[10] + p[11]);
      float t3 = (p[12] + p[13]) + (p[14] + p[15]);
      float u0 = (q[0] + q[1]) + (q[2] + q[3]);
      float u1 = (q[4] + q[5]) + (q[6] + q[7]);
      float u2 = (q[8] + q[9]) + (q[10] + q[11]);
      float u3 = (q[12] + q[13]) + (q[14] + q[15]);
      l_s += ((t0 + t1) + (t2 + t3)) + ((u0 + u1) + (u2 + u3));
      #pragma unroll
      for (int rg = 0; rg < 4; ++rg) {
        Pp[0][rg][0] = pk2bf(p[4 * rg + 0], p[4 * rg + 1]);
        Pp[0][rg][1] = pk2bf(p[4 * rg + 2], p[4 * rg + 3]);
        Pp[1][rg][0] = pk2bf(q[4 * rg + 0], q[4 * rg + 1]);
        Pp[1][rg][1] = pk2bf(q[4 * rg + 2], q[4 * rg + 3]);
      }
    }

    // ctx^T += V^T P^T: 4 ksteps over 64 s' (ksg), both d-halves
    __builtin_amdgcn_s_setprio(1);
    #pragma unroll
    for (int ksg = 0; ksg < 4; ++ksg) {
      const int hs = ksg >> 1, p2 = ksg & 1;
      u32 a0 = Pp[hs][2 * p2][0], b0 = Pp[hs][2 * p2 + 1][0];
      u32 a1 = Pp[hs][2 * p2][1], b1 = Pp[hs][2 * p2 + 1][1];
      asm("v_permlane32_swap_b32 %0, %1" : "+v"(a0), "+v"(b0));
      asm("v_permlane32_swap_b32 %0, %1" : "+v"(a1), "+v"(b1));
      u32x4 fw;
      fw.x = a0; fw.y = a1; fw.z = b0; fw.w = b1;
      bf16x8 pf = __builtin_bit_cast(bf16x8, fw);
      const int gp = ((2 * ksg + h) ^ (l31 & 7) ^ ((l31 >> 3) & 3)) * 8;
      bf16x8 vf0 = *(const bf16x8*)&Vl[l31 * 64 + gp];
      bf16x8 vf1 = *(const bf16x8*)&Vl[(32 + l31) * 64 + gp];
      cacc[0] = __builtin_amdgcn_mfma_f32_32x32x16_bf16(vf0, pf, cacc[0], 0, 0, 0);
      cacc[1] = __builtin_amdgcn_mfma_f32_32x32x16_bf16(vf1, pf, cacc[1], 0, 0, 0);
    }
    __builtin_amdgcn_s_setprio(0);
    __syncthreads();   // buffer-swap fence + prefetch drain
  }

  // ----- epilogue: cacc is final per wave; direct scaled store -----
  const float lq = l_s + __shfl_xor(l_s, 32, 64);
  const float inv = 1.0f / lq;
  const int b = bh >> 4, hd = bh & 15;
  const int s = q0 + w * 32 + l31;
  #pragma unroll
  for (int dt = 0; dt < 2; ++dt) {
    #pragma unroll
    for (int c = 0; c < 4; ++c) {
      const int d0 = dt * 32 + c * 8 + 4 * h;
      ushort4 pk;
      pk.x = f2bf(cacc[dt][4 * c + 0] * inv);
      pk.y = f2bf(cacc[dt][4 * c + 1] * inv);
      pk.z = f2bf(cacc[dt][4 * c + 2] * inv);
      pk.w = f2bf(cacc[dt][4 * c + 3] * inv);
      *(ushort4*)&ctx[(size_t)(b * SQ + s) * DM + hd * DH + d0] = pk;
    }
  }
}

// ------------- 128x64 NT-GEMM core (A=128 rows, B=64 rows, BK=64) ------------
__device__ __forceinline__ void gemm_core_128x64(
    u16* lds, const u16* __restrict__ Ab, const u16* __restrict__ Bb,
    f32x4 acc[4][2])
{
  u16* As = lds;            // [128][64]
  u16* Bs = lds + 8192;     // [64][64]
  const int tid = threadIdx.x, lane = tid & 63, w = tid >> 6;
  const int waveM = w >> 1, waveN = w & 1;
  const int col = lane & 15, quad = lane >> 4;
  const int srow = lane >> 3;
  const int sg0  = (lane & 7) ^ srow;

  for (int k0 = 0; k0 < DM; k0 += 64) {
    #pragma unroll
    for (int i = 0; i < 4; ++i) {
      const int rb = w * 32 + i * 8;
      const int sg = sg0 ^ ((rb >> 3) & 3);
      gld16(Ab + (size_t)(rb + srow) * DM + k0 + sg * 8, &As[rb * 64]);
    }
    #pragma unroll
    for (int i = 0; i < 2; ++i) {
      const int rb = w * 16 + i * 8;
      const int sg = sg0 ^ ((rb >> 3) & 3);
      gld16(Bb + (size_t)(rb + srow) * DM + k0 + sg * 8, &Bs[rb * 64]);
    }
    __syncthreads();
    #pragma unroll
    for (int c = 0; c < 2; ++c) {
      bf16x8 af[4], bg[2];
      #pragma unroll
      for (int i = 0; i < 4; ++i) {
        const int row = waveM * 64 + i * 16 + col;
        const int gp = (c * 4 + quad) ^ (row & 7) ^ ((row >> 3) & 3);
        af[i] = *(const bf16x8*)&As[row * 64 + gp * 8];
      }
      #pragma unroll
      for (int j = 0; j < 2; ++j) {
        const int row = waveN * 32 + j * 16 + col;
        const int gp = (c * 4 + quad) ^ (row & 7) ^ ((row >> 3) & 3);
        bg[j] = *(const bf16x8*)&Bs[row * 64 + gp * 8];
      }
      #pragma unroll
      for (int i = 0; i < 4; ++i) {
        #pragma unroll
        for (int j = 0; j < 2; ++j)
          acc[i][j] = __builtin_amdgcn_mfma_f32_16x16x32_bf16(af[i], bg[j], acc[i][j], 0, 0, 0);
      }
    }
    __syncthreads();
  }
}

// -------- k5: output projection (128x64 tiles, BK=64 swizzled, fp32 out) -----
// grid (32, 16) — token-block on x so XCD = token-group.
__global__ __launch_bounds__(256) void gemm_out_kernel(
    const u16* __restrict__ ctx, const u16* __restrict__ Wob,
    const float* __restrict__ bo, float* __restrict__ out)
{
  __shared__ __align__(16) u16 smem[128 * 64 + 64 * 64];  // 24 KB
  const int tb = blockIdx.x;                 // token-block (32)
  const int cb = blockIdx.y;                 // channel-block (16)
  const int tid = threadIdx.x, lane = tid & 63, w = tid >> 6;
  const int waveM = w >> 1, waveN = w & 1;
  const int col = lane & 15, quad = lane >> 4;

  f32x4 acc[4][2];
  const f32x4 zf = {0.f, 0.f, 0.f, 0.f};
  #pragma unroll
  for (int i = 0; i < 4; ++i) {
    #pragma unroll
    for (int j = 0; j < 2; ++j) acc[i][j] = zf;
  }

  gemm_core_128x64(smem, ctx + (size_t)(tb * 128) * DM,
                   Wob + (size_t)(cb * 64) * DM, acc);

  const int rowBase = tb * 128 + waveM * 64;   // A side = tokens
  const int colBase = cb * 64 + waveN * 32;    // B side = channels
  #pragma unroll
  for (int j = 0; j < 2; ++j) {
    const int c = colBase + j * 16 + col;
    const float bb = bo[c];
    #pragma unroll
    for (int i = 0; i < 4; ++i) {
      #pragma unroll
      for (int r = 0; r < 4; ++r) {
        const int t = rowBase + i * 16 + quad * 4 + r;
        out[(size_t)t * DM + c] = acc[i][j][r] + bb;
      }
    }
  }
}

extern "C" void kernel_launch(void* const* d_in, const int* in_sizes, int n_in,
                              void* d_out, int out_size, void* d_ws, size_t ws_size,
                              hipStream_t stream) {
  const float* x  = (const float*)d_in[0];
  const float* Wq = (const float*)d_in[1];
  const float* bq = (const float*)d_in[2];
  const float* Wk = (const float*)d_in[3];
  const float* bk = (const float*)d_in[4];
  const float* Wv = (const float*)d_in[5];
  const float* bv = (const float*)d_in[6];
  const float* Wo = (const float*)d_in[7];
  const float* bo = (const float*)d_in[8];

  char* ws = (char*)d_ws;                  // 40 MB used
  u16* xb  = (u16*)(ws);                   // 8 MB  (reused as ctx after QKV)
  u16* Wqb = (u16*)(ws + (8ull  << 20));   // 2 MB
  u16* Wkb = (u16*)(ws + (10ull << 20));   // 2 MB
  u16* Wvb = (u16*)(ws + (12ull << 20));   // 2 MB
  u16* Wob = (u16*)(ws + (14ull << 20));   // 2 MB
  u16* Qs  = (u16*)(ws + (16ull << 20));   // 8 MB  [b,h,s,d], pre-scaled
  u16* Kh  = (u16*)(ws + (24ull << 20));   // 8 MB  [b,h,s,d]
  u16* Vt  = (u16*)(ws + (32ull << 20));   // 8 MB  [b,h,d,s]
  u16* ctx = xb;                           // alias: xb dead after QKV GEMM

  cast_bf16_kernel<<<dim3(256, 5), 256, 0, stream>>>(x, Wq, Wk, Wv, Wo,
                                                     xb, Wqb, Wkb, Wvb, Wob);
  gemm_qkv_kernel<<<dim3(32, 8, 2), 256, 0, stream>>>(xb, Wqb, Wkb, Wvb,
                                                      bq, bk, bv, Qs, Kh, Vt);
  attn_kernel<<<dim3(32, 16), 256, 0, stream>>>(Qs, Kh, Vt, ctx);
  gemm_out_kernel<<<dim3(32, 16), 256, 0, stream>>>(ctx, Wob, bo, (float*)d_out);
  (void)in_sizes; (void)n_in; (void)out_size; (void)ws_size;
}